// Round 1
// baseline (3345.640 us; speedup 1.0000x reference)
//
#include <hip/hip_runtime.h>
#include <math.h>

// Problem dims: B=8, NS=32, L=128, H=768, LH=256, C=4
// N_SEQ = B*NS = 256 word-level sequences, gate width G4 = 4*LH = 1024.

#define G4 1024

__device__ __forceinline__ float sigmoidf_(float x) { return 1.0f / (1.0f + expf(-x)); }

// ---------------------------------------------------------------------------
// zero helper (harness poisons d_ws with 0xAA before every call)
__global__ void zero_f4(float4* __restrict__ p, int n) {
    int i = blockIdx.x * 256 + threadIdx.x;
    if (i < n) p[i] = make_float4(0.f, 0.f, 0.f, 0.f);
}

// ---------------------------------------------------------------------------
// transpose sentence-level W_hh (2 x [1024][256]) -> Wt[dir][k][j] (2 x [256][1024])
__global__ void transpose_whh(const float* __restrict__ Wf, const float* __restrict__ Wb,
                              float* __restrict__ Wt) {
    int idx = blockIdx.x * 256 + threadIdx.x;
    if (idx >= 524288) return;
    int dir = idx >> 18;
    int rem = idx & 262143;
    int k = rem >> 10;
    int j = rem & 1023;
    const float* Wp = dir ? Wb : Wf;
    Wt[idx] = Wp[j * 256 + k];
}

// ---------------------------------------------------------------------------
// Generic fused input-projection GEMM:
//   Out[m][j] = sum_k A[m][k] * W[j][k] + bias[j]
// N = 2048 (cols 0..1023 -> forward weights/out, 1024..2047 -> backward).
// BM=BN=128, BK=16, 256 threads, 8x8 micro-tile in 2x(4) split blocks
// (split-block avoids the 4-way LDS bank conflict of a contiguous 8-wide read).
__global__ __launch_bounds__(256) void gemm_proj(
    const float* __restrict__ A, int M, int K,
    const float* __restrict__ Wf, const float* __restrict__ Wb,
    const float* __restrict__ bf, const float* __restrict__ bb,
    float* __restrict__ Of, float* __restrict__ Ob)
{
    __shared__ float As[16][132];
    __shared__ float Bs[16][132];
    const int t = threadIdx.x;
    const int n0 = blockIdx.x * 128;   // 0..1920 ; tiles never straddle the 1024 boundary
    const int m0 = blockIdx.y * 128;
    const int sel = (n0 >= 1024);
    const float* Wp = sel ? Wb : Wf;
    const float* bp = sel ? bb : bf;
    float* Op = sel ? Ob : Of;
    const int n0d = n0 & 1023;

    const int tm = t >> 4;   // 0..15
    const int tn = t & 15;   // 0..15

    float acc[8][8];
#pragma unroll
    for (int i = 0; i < 8; i++)
#pragma unroll
        for (int j = 0; j < 8; j++) acc[i][j] = 0.f;

    for (int k0 = 0; k0 < K; k0 += 16) {
        __syncthreads();
#pragma unroll
        for (int rr = 0; rr < 2; rr++) {   // A tile: 128 rows x 16 k
            int idx = t + rr * 256;
            int row = idx >> 2, kq = idx & 3;
            float4 v = *(const float4*)&A[(size_t)(m0 + row) * K + k0 + kq * 4];
            As[kq * 4 + 0][row] = v.x; As[kq * 4 + 1][row] = v.y;
            As[kq * 4 + 2][row] = v.z; As[kq * 4 + 3][row] = v.w;
        }
#pragma unroll
        for (int rr = 0; rr < 2; rr++) {   // W tile: 128 rows x 16 k
            int idx = t + rr * 256;
            int row = idx >> 2, kq = idx & 3;
            float4 v = *(const float4*)&Wp[(size_t)(n0d + row) * K + k0 + kq * 4];
            Bs[kq * 4 + 0][row] = v.x; Bs[kq * 4 + 1][row] = v.y;
            Bs[kq * 4 + 2][row] = v.z; Bs[kq * 4 + 3][row] = v.w;
        }
        __syncthreads();
#pragma unroll
        for (int k = 0; k < 16; k++) {
            float4 a0 = *(const float4*)&As[k][tm * 4];
            float4 a1 = *(const float4*)&As[k][tm * 4 + 64];
            float4 b0 = *(const float4*)&Bs[k][tn * 4];
            float4 b1 = *(const float4*)&Bs[k][tn * 4 + 64];
            float av[8] = {a0.x, a0.y, a0.z, a0.w, a1.x, a1.y, a1.z, a1.w};
            float bv[8] = {b0.x, b0.y, b0.z, b0.w, b1.x, b1.y, b1.z, b1.w};
#pragma unroll
            for (int i = 0; i < 8; i++)
#pragma unroll
                for (int j = 0; j < 8; j++)
                    acc[i][j] += av[i] * bv[j];
        }
    }

#pragma unroll
    for (int ih = 0; ih < 2; ih++) {
#pragma unroll
        for (int i = 0; i < 4; i++) {
            int m = m0 + ih * 64 + tm * 4 + i;
#pragma unroll
            for (int jh = 0; jh < 2; jh++) {
                int col = n0d + jh * 64 + tn * 4;
                float4 bias4 = *(const float4*)&bp[col];
                float4 r;
                r.x = acc[ih * 4 + i][jh * 4 + 0] + bias4.x;
                r.y = acc[ih * 4 + i][jh * 4 + 1] + bias4.y;
                r.z = acc[ih * 4 + i][jh * 4 + 2] + bias4.z;
                r.w = acc[ih * 4 + i][jh * 4 + 3] + bias4.w;
                *(float4*)&Op[(size_t)m * G4 + col] = r;
            }
        }
    }
}

// ---------------------------------------------------------------------------
// One word-LSTM timestep (both directions fused in the grid).
// Grid: 256 WGs = dir(2) x seq-tile(16 of 16 seqs) x unit-tile(8 of 32 units).
// Each WG: gates = 4 types x 32 units (128 rows) x 16 seqs, K=256 over h_in,
// then fused cell update + masked-pool accumulation.
__global__ __launch_bounds__(256) void word_step(
    const float* __restrict__ Gf, const float* __restrict__ Gb,
    const float* __restrict__ Whf, const float* __restrict__ Whb,
    const int* __restrict__ mask,
    const float* __restrict__ h_in, float* __restrict__ h_out,
    float* __restrict__ c_st, float* __restrict__ pooled, int t)
{
    __shared__ float As[16][68];     // h tile: 16 seqs x 64 k
    __shared__ float Ws[128][68];    // weight tile: 128 gate rows x 64 k
    __shared__ float Gex[128][17];   // gate exchange [row][seq]

    const int tid = threadIdx.x;
    const int bx = blockIdx.x;
    const int dir = bx >> 7;
    const int r = bx & 127;
    const int st = r >> 3;
    const int ut = r & 7;
    const int seq0 = st * 16;
    const int u0 = ut * 32;
    const int t_eff = dir ? (127 - t) : t;
    const float* W = dir ? Whb : Whf;
    const float* G = dir ? Gb : Gf;
    const int hbase = dir * 65536;

    // thread computes 2 seqs x (4 gate rows of one unit): rows {uu,32+uu,64+uu,96+uu}
    const int tcol = tid & 7;
    const int uu = tid >> 3;       // 0..31
    const int s0 = tcol * 2;

    float acc[2][4] = {{0, 0, 0, 0}, {0, 0, 0, 0}};

    for (int kc = 0; kc < 4; kc++) {
        int k0 = kc * 64;
        __syncthreads();
        {   // stage h tile (16x64)
            int row = tid >> 4, kq = tid & 15;
            float4 v = *(const float4*)&h_in[hbase + (seq0 + row) * 256 + k0 + kq * 4];
            *(float4*)&As[row][kq * 4] = v;
        }
#pragma unroll
        for (int i = 0; i < 8; i++) {   // stage weight tile (128x64)
            int idx = tid + i * 256;
            int row = idx >> 4, kq = idx & 15;
            int j = ((row >> 5) << 8) + u0 + (row & 31);  // gate row -> global row
            float4 v = *(const float4*)&W[j * 256 + k0 + kq * 4];
            *(float4*)&Ws[row][kq * 4] = v;
        }
        __syncthreads();
#pragma unroll
        for (int k = 0; k < 64; k += 4) {
            float4 a0 = *(const float4*)&As[s0][k];
            float4 a1 = *(const float4*)&As[s0 + 1][k];
#pragma unroll
            for (int g = 0; g < 4; g++) {
                float4 w = *(const float4*)&Ws[g * 32 + uu][k];
                acc[0][g] += a0.x * w.x + a0.y * w.y + a0.z * w.z + a0.w * w.w;
                acc[1][g] += a1.x * w.x + a1.y * w.y + a1.z * w.z + a1.w * w.w;
            }
        }
    }

    __syncthreads();
#pragma unroll
    for (int g = 0; g < 4; g++) {
        Gex[g * 32 + uu][s0]     = acc[0][g];
        Gex[g * 32 + uu][s0 + 1] = acc[1][g];
    }
    __syncthreads();

#pragma unroll
    for (int half = 0; half < 2; half++) {
        int cu = tid + half * 256;
        int u2 = cu & 31, s = cu >> 5;
        int n = seq0 + s;
        size_t gbase = (size_t)(n * 128 + t_eff) * 1024 + u0 + u2;
        float iv = Gex[u2][s]        + G[gbase];
        float fv = Gex[32 + u2][s]   + G[gbase + 256];
        float gv = Gex[64 + u2][s]   + G[gbase + 512];
        float ov = Gex[96 + u2][s]   + G[gbase + 768];
        int ci = hbase + n * 256 + u0 + u2;
        float cold = c_st[ci];
        float cn = sigmoidf_(fv) * cold + sigmoidf_(iv) * tanhf(gv);
        float hn = sigmoidf_(ov) * tanhf(cn);
        c_st[ci] = cn;
        h_out[ci] = hn;
        if (mask[n * 128 + t_eff] != 0)
            pooled[n * 512 + dir * 256 + u0 + u2] += hn;
    }
}

// ---------------------------------------------------------------------------
// masked-mean division: pooled (256 x 512) /= max(cnt,1)   (cnt==0 rows stay 0)
__global__ __launch_bounds__(256) void pool_div(float* __restrict__ pooled,
                                                const int* __restrict__ mask) {
    __shared__ float red[256];
    int n = blockIdx.x, t = threadIdx.x;
    red[t] = (t < 128) ? (float)mask[n * 128 + t] : 0.f;
    __syncthreads();
    for (int off = 128; off > 0; off >>= 1) {
        if (t < off) red[t] += red[t + off];
        __syncthreads();
    }
    float inv = 1.0f / fmaxf(red[0], 1.0f);
    pooled[n * 512 + t] *= inv;
    pooled[n * 512 + 256 + t] *= inv;
}

// ---------------------------------------------------------------------------
// One sentence-LSTM timestep. Grid: 128 WGs = dir(2) x b(8) x unit-tile(8 of 32).
// Uses transposed Wt[dir][k][j] for coalesced weight reads from L2.
__global__ __launch_bounds__(256) void sent_step(
    const float* __restrict__ Gsf, const float* __restrict__ Gsb,
    const float* __restrict__ Wt,
    const float* __restrict__ h_in, float* __restrict__ h_out,
    float* __restrict__ c_s, float* __restrict__ final_h, int s)
{
    __shared__ float h_lds[256];
    __shared__ float part[256];
    __shared__ float ex[4][33];
    const int tid = threadIdx.x;
    const int bx = blockIdx.x;
    const int dir = bx >> 6;
    const int rb = bx & 63;
    const int b = rb >> 3;
    const int ut = rb & 7;
    const int u0 = ut * 32;
    const int t_eff = dir ? (31 - s) : s;
    const float* Gs = dir ? Gsb : Gsf;

    if (tid < 64) {
        float4 v = *(const float4*)&h_in[dir * 2048 + b * 256 + tid * 4];
        *(float4*)&h_lds[tid * 4] = v;
    }
    __syncthreads();

    const int kh = tid >> 7;      // k half
    const int rr = tid & 127;     // gate row within tile
    const int g = rr >> 5;
    const int uu = rr & 31;
    const int j = g * 256 + u0 + uu;
    const float* wp = Wt + dir * 262144 + kh * 128 * 1024 + j;
    float acc = 0.f;
#pragma unroll 8
    for (int k = 0; k < 128; k++)
        acc += wp[k * 1024] * h_lds[kh * 128 + k];
    part[tid] = acc;
    __syncthreads();
    if (tid < 128) ex[g][uu] = part[tid] + part[tid + 128];
    __syncthreads();

    if (tid < 32) {
        int u = u0 + tid;
        size_t gb = (size_t)(b * 32 + t_eff) * 1024 + u;
        float iv = ex[0][tid] + Gs[gb];
        float fv = ex[1][tid] + Gs[gb + 256];
        float gv = ex[2][tid] + Gs[gb + 512];
        float ov = ex[3][tid] + Gs[gb + 768];
        int ci = dir * 2048 + b * 256 + u;
        float cold = c_s[ci];
        float cn = sigmoidf_(fv) * cold + sigmoidf_(iv) * tanhf(gv);
        float hn = sigmoidf_(ov) * tanhf(cn);
        c_s[ci] = cn;
        h_out[ci] = hn;
        if (t_eff == 31) final_h[b * 512 + dir * 256 + u] = hn;
    }
}

// ---------------------------------------------------------------------------
// logits: (8x512) @ (4x512)^T + bias -> 32 outputs
__global__ __launch_bounds__(256) void logits_k(const float* __restrict__ fh,
                                                const float* __restrict__ cw,
                                                const float* __restrict__ cb,
                                                float* __restrict__ out) {
    __shared__ float red[256];
    int tid = threadIdx.x;
    int o = tid >> 3;          // 0..31 : o = b*4 + c
    int b = o >> 2; int c = o & 3;
    int p = tid & 7;
    float acc = 0.f;
    const float* fv = fh + b * 512 + p * 64;
    const float* wv = cw + c * 512 + p * 64;
#pragma unroll 8
    for (int e = 0; e < 64; e++) acc += fv[e] * wv[e];
    red[tid] = acc;
    __syncthreads();
    if (p == 0) {
        float s = 0.f;
#pragma unroll
        for (int q = 0; q < 8; q++) s += red[o * 8 + q];
        out[o] = s + cb[c];
    }
}

// ---------------------------------------------------------------------------
extern "C" void kernel_launch(void* const* d_in, const int* in_sizes, int n_in,
                              void* d_out, int out_size, void* d_ws, size_t ws_size,
                              hipStream_t stream) {
    const float* X       = (const float*)d_in[0];
    const int*   mask    = (const int*)d_in[1];
    const float* wl_ih_f = (const float*)d_in[2];
    const float* wl_hh_f = (const float*)d_in[3];
    const float* wl_b_f  = (const float*)d_in[4];
    const float* wl_ih_b = (const float*)d_in[5];
    const float* wl_hh_b = (const float*)d_in[6];
    const float* wl_b_b  = (const float*)d_in[7];
    const float* ws_ih_f = (const float*)d_in[8];
    const float* ws_hh_f = (const float*)d_in[9];
    const float* ws_b_f  = (const float*)d_in[10];
    const float* ws_ih_b = (const float*)d_in[11];
    const float* ws_hh_b = (const float*)d_in[12];
    const float* ws_b_b  = (const float*)d_in[13];
    const float* cls_w   = (const float*)d_in[14];
    const float* cls_b   = (const float*)d_in[15];
    float* out = (float*)d_out;
    float* w = (float*)d_ws;

    // workspace layout (floats)
    float* Gf     = w;                    // 256*128*1024
    float* Gb     = Gf + 33554432;
    float* Gsf    = Gb + 33554432;        // 256*1024
    float* Gsb    = Gsf + 262144;
    float* Wt     = Gsb + 262144;         // 2*256*1024 transposed sentence W_hh
    float* finalh = Wt + 524288;          // 8*512
    // ---- zero-initialized region (contiguous) ----
    float* h0     = finalh + 4096;        // 2*256*256
    float* h1     = h0 + 131072;
    float* c_st   = h1 + 131072;
    float* pooled = c_st + 131072;        // 256*512
    float* hs0    = pooled + 131072;      // 2*8*256
    float* hs1    = hs0 + 4096;
    float* cs     = hs1 + 4096;
    (void)cs; (void)in_sizes; (void)n_in; (void)out_size; (void)ws_size;

    // zero h0,h1,c_st,pooled,hs0,hs1,cs = 536576 floats = 134144 float4
    zero_f4<<<524, 256, 0, stream>>>((float4*)h0, 134144);
    transpose_whh<<<2048, 256, 0, stream>>>(ws_hh_f, ws_hh_b, Wt);

    // word-level input projection: (32768x768) @ (768x2048) + bias
    gemm_proj<<<dim3(16, 256), 256, 0, stream>>>(X, 32768, 768,
                                                 wl_ih_f, wl_ih_b, wl_b_f, wl_b_b, Gf, Gb);

    // word-level recurrence, 128 steps (both directions per launch)
    for (int t = 0; t < 128; t++) {
        float* hin  = (t & 1) ? h1 : h0;
        float* hout = (t & 1) ? h0 : h1;
        word_step<<<256, 256, 0, stream>>>(Gf, Gb, wl_hh_f, wl_hh_b, mask,
                                           hin, hout, c_st, pooled, t);
    }

    pool_div<<<256, 256, 0, stream>>>(pooled, mask);

    // sentence-level input projection: (256x512) @ (512x2048) + bias
    gemm_proj<<<dim3(16, 2), 256, 0, stream>>>(pooled, 256, 512,
                                               ws_ih_f, ws_ih_b, ws_b_f, ws_b_b, Gsf, Gsb);

    // sentence-level recurrence, 32 steps
    for (int s = 0; s < 32; s++) {
        float* hin  = (s & 1) ? hs1 : hs0;
        float* hout = (s & 1) ? hs0 : hs1;
        sent_step<<<128, 256, 0, stream>>>(Gsf, Gsb, Wt, hin, hout, cs, finalh, s);
    }

    logits_k<<<1, 256, 0, stream>>>(finalh, cls_w, cls_b, out);
}